// Round 7
// baseline (213.805 us; speedup 1.0000x reference)
//
#include <hip/hip_runtime.h>
#include <hip/hip_bf16.h>
#include <math.h>

// Problem constants (fixed by setup_inputs)
#define CIN      8
#define H_IN     100
#define W_IN     136
#define NPIX     (H_IN * W_IN)       // 13600
#define OH       (2 * H_IN)          // 200
#define OW       (2 * W_IN)          // 272
#define ONPIX    (OH * OW)           // 54400
#define NPARAMS  169
#define EPSV     1e-5f
#define NSLICE   4                   // row-slices per instance
#define KG4      34                  // 136/4 col-groups of 4 src px
#define KGROUPS  34                  // 272/8 output col-groups
#define TASKS_A  (25 * KG4)          // 850 phase-A tasks per block (25 rows)
#define TASKS_B  (25 * KGROUPS)      // 850 phase-B tasks per block (25 row-pairs)

// param layout: w0[8][10] @0, w1[8][8] @80, w2[8] @144, b0 @152, b1 @160, b2 @168

__device__ __forceinline__ float sigmoidf_fast(float x) {
    float e = __expf(-x);
    return __builtin_amdgcn_rcpf(1.f + e);
}

// ============================ Kernel A: logits ==============================
// 4 blocks/instance, 25 disjoint rows each (no border recompute — kernel B
// reads neighbor rows from the global logit buffer). FMA-dense: wants VGPR/ILP,
// loose (256,2) cap (R2: tight caps spill; R4: mid caps serialize).
__global__ __launch_bounds__(256, 2)
void mask_logits(const float* __restrict__ mask_feats,   // [N,8,100,136]
                 const float* __restrict__ params,       // [n,169]
                 const float* __restrict__ locs,         // [n,2]
                 const int*   __restrict__ im_inds,      // [n]
                 const int*   __restrict__ fpn_levels,   // [n]
                 float*       __restrict__ logits)       // [n,100,136]
{
    const int inst  = blockIdx.x >> 2;
    const int slice = blockIdx.x & 3;
    const int tid   = threadIdx.x;
    const int row0  = 25 * slice;

    const float* __restrict__ wp = params + (size_t)inst * NPARAMS;  // scalar K$

    const int   im  = im_inds[inst];
    const int   lvl = fpn_levels[inst];
    const float inv_soi = exp2f(-(float)(3 + lvl));  // SOI = 8*2^lvl, exact
    const float lx = locs[inst * 2 + 0];
    const float ly = locs[inst * 2 + 1];
    const float dx8 = 8.f * inv_soi;

    const float* feat = mask_feats + (size_t)im * (CIN * NPIX);
    float* lg = logits + (size_t)inst * NPIX;

    #pragma unroll 1
    for (int it = 0; it < 4; ++it) {
        const int t = it * 256 + tid;
        if (t >= TASKS_A) break;               // only last iteration partial
        const int r  = t / KG4;                // local row 0..24
        const int k  = t - r * KG4;            // col-group 0..33
        const int row = row0 + r;
        const int px  = row * W_IN + 4 * k;
        const float* fb = feat + px;

        // 8 independent 16B loads issued upfront
        float4 f0 = *(const float4*)(fb);
        float4 f1 = *(const float4*)(fb + NPIX);
        float4 f2 = *(const float4*)(fb + 2 * NPIX);
        float4 f3 = *(const float4*)(fb + 3 * NPIX);
        float4 f4 = *(const float4*)(fb + 4 * NPIX);
        float4 f5 = *(const float4*)(fb + 5 * NPIX);
        float4 f6 = *(const float4*)(fb + 6 * NPIX);
        float4 f7 = *(const float4*)(fb + 7 * NPIX);

        float in0[4];
        in0[0] = (lx - (float)(32 * k + 4)) * inv_soi;
        in0[1] = in0[0] - dx8;
        in0[2] = in0[1] - dx8;
        in0[3] = in0[2] - dx8;
        const float in1 = (ly - (float)(row * 8 + 4)) * inv_soi;

        // layer 0: 10 -> 8
        float a[8][4];
        #pragma unroll
        for (int o = 0; o < 8; ++o) {
            const float base = fmaf(wp[o * 10 + 1], in1, wp[152 + o]);
            const float w0 = wp[o * 10 + 0];
            #pragma unroll
            for (int j = 0; j < 4; ++j)
                a[o][j] = fmaf(w0, in0[j], base);
        }
        float f[8][4];
        f[0][0]=f0.x; f[0][1]=f0.y; f[0][2]=f0.z; f[0][3]=f0.w;
        f[1][0]=f1.x; f[1][1]=f1.y; f[1][2]=f1.z; f[1][3]=f1.w;
        f[2][0]=f2.x; f[2][1]=f2.y; f[2][2]=f2.z; f[2][3]=f2.w;
        f[3][0]=f3.x; f[3][1]=f3.y; f[3][2]=f3.z; f[3][3]=f3.w;
        f[4][0]=f4.x; f[4][1]=f4.y; f[4][2]=f4.z; f[4][3]=f4.w;
        f[5][0]=f5.x; f[5][1]=f5.y; f[5][2]=f5.z; f[5][3]=f5.w;
        f[6][0]=f6.x; f[6][1]=f6.y; f[6][2]=f6.z; f[6][3]=f6.w;
        f[7][0]=f7.x; f[7][1]=f7.y; f[7][2]=f7.z; f[7][3]=f7.w;
        #pragma unroll
        for (int c = 0; c < CIN; ++c) {
            #pragma unroll
            for (int o = 0; o < 8; ++o) {
                const float w = wp[o * 10 + 2 + c];
                #pragma unroll
                for (int j = 0; j < 4; ++j)
                    a[o][j] = fmaf(w, f[c][j], a[o][j]);
            }
        }
        #pragma unroll
        for (int o = 0; o < 8; ++o)
            #pragma unroll
            for (int j = 0; j < 4; ++j)
                a[o][j] = fmaxf(a[o][j], 0.f);

        // layer 1: 8 -> 8 (relu folded into layer-2 consumption)
        float h[8][4];
        #pragma unroll
        for (int o = 0; o < 8; ++o) {
            const float b = wp[160 + o];
            #pragma unroll
            for (int j = 0; j < 4; ++j) h[o][j] = b;
        }
        #pragma unroll
        for (int i = 0; i < 8; ++i) {
            #pragma unroll
            for (int o = 0; o < 8; ++o) {
                const float w = wp[80 + o * 8 + i];
                #pragma unroll
                for (int j = 0; j < 4; ++j)
                    h[o][j] = fmaf(w, a[i][j], h[o][j]);
            }
        }

        // layer 2: 8 -> 1
        const float b2 = wp[168];
        float o4[4] = {b2, b2, b2, b2};
        #pragma unroll
        for (int i = 0; i < 8; ++i) {
            const float w = wp[144 + i];
            #pragma unroll
            for (int j = 0; j < 4; ++j)
                o4[j] = fmaf(w, fmaxf(h[i][j], 0.f), o4[j]);
        }

        float4 ov = {o4[0], o4[1], o4[2], o4[3]};
        *(float4*)(lg + px) = ov;             // 16B-aligned global store
    }
}

// ================= Kernel B: x2 upsample + sigmoid + dice ===================
// Streaming kernel: gt from HBM/L3, logits from L3/L2. Slim (~55 VGPR) so
// 3 blocks/CU hide memory latency with TLP. No phase barrier.
__global__ __launch_bounds__(256, 3)
void dice_reduce(const float* __restrict__ logits,    // [n,100,136]
                 const float* __restrict__ gt,        // [n,1,200,272]
                 float*       __restrict__ partials)  // [n*4][3]
{
    const int inst  = blockIdx.x >> 2;
    const int slice = blockIdx.x & 3;
    const int tid   = threadIdx.x;
    const int pair_base = 25 * slice;

    __shared__ float s_red[12];

    const float* lg  = logits + (size_t)inst * NPIX;
    const float* gtp = gt + (size_t)inst * ONPIX;

    float inter = 0.f, ssum = 0.f, tsum = 0.f;

    #pragma unroll 1
    for (int it = 0; it < 4; ++it) {
        const int t = it * 256 + tid;
        if (t >= TASKS_B) break;
        const int pl = t / KGROUPS;
        const int k  = t - pl * KGROUPS;
        const int pg = pair_base + pl;                 // global row-pair 0..99
        const float* E = lg + pg * W_IN;               // exact src row
        const float* P = lg + (pg > 0 ? pg - 1 : 0) * W_IN;  // prev src row
        const int c0  = 4 * k;
        const int cm1 = (k > 0) ? c0 - 1 : 0;

        // issue all loads upfront: 4 gt float4 + 2 logit float4 + 2 scalars
        const float* g0 = gtp + (size_t)(2 * pg) * OW + 8 * k;
        const float4 ga = *(const float4*)(g0);            // avg row, cols 0-3
        const float4 gb = *(const float4*)(g0 + 4);        // avg row, cols 4-7
        const float4 gc = *(const float4*)(g0 + OW);       // exact row, cols 0-3
        const float4 gd = *(const float4*)(g0 + OW + 4);   // exact row, cols 4-7
        const float4 e4 = *(const float4*)(E + c0);
        const float  em = E[cm1];
        const float4 p4 = *(const float4*)(P + c0);
        const float  pm = P[cm1];

        const float ecur[4] = {e4.x, e4.y, e4.z, e4.w};
        const float pcur[4] = {p4.x, p4.y, p4.z, p4.w};
        const float gav[8] = {ga.x, ga.y, ga.z, ga.w, gb.x, gb.y, gb.z, gb.w};
        const float gex[8] = {gc.x, gc.y, gc.z, gc.w, gd.x, gd.y, gd.z, gd.w};

        // Output row 2p = avg(src p-1, src p); row 2p+1 = src p.
        // Cols: o[2j]=avg adjacent src cols, o[2j+1]=src col (left edge clamp).
        float Se_prev = em;
        float Sa_prev = 0.5f * (em + pm);
        #pragma unroll
        for (int j = 0; j < 4; ++j) {
            const float Se = ecur[j];
            const float Sa = 0.5f * (ecur[j] + pcur[j]);
            {
                float s = sigmoidf_fast(0.5f * (Sa_prev + Sa));
                float t2 = gav[2 * j];
                inter = fmaf(s, t2, inter); ssum = fmaf(s, s, ssum); tsum = fmaf(t2, t2, tsum);
                s = sigmoidf_fast(Sa);
                t2 = gav[2 * j + 1];
                inter = fmaf(s, t2, inter); ssum = fmaf(s, s, ssum); tsum = fmaf(t2, t2, tsum);
            }
            {
                float s = sigmoidf_fast(0.5f * (Se_prev + Se));
                float t2 = gex[2 * j];
                inter = fmaf(s, t2, inter); ssum = fmaf(s, s, ssum); tsum = fmaf(t2, t2, tsum);
                s = sigmoidf_fast(Se);
                t2 = gex[2 * j + 1];
                inter = fmaf(s, t2, inter); ssum = fmaf(s, s, ssum); tsum = fmaf(t2, t2, tsum);
            }
            Se_prev = Se;
            Sa_prev = Sa;
        }
    }

    // block reduction (4 waves of 64)
    #pragma unroll
    for (int off = 32; off > 0; off >>= 1) {
        inter += __shfl_down(inter, off, 64);
        ssum  += __shfl_down(ssum,  off, 64);
        tsum  += __shfl_down(tsum,  off, 64);
    }
    const int wid = tid >> 6;
    if ((tid & 63) == 0) {
        s_red[wid * 3 + 0] = inter;
        s_red[wid * 3 + 1] = ssum;
        s_red[wid * 3 + 2] = tsum;
    }
    __syncthreads();
    if (tid == 0) {
        float I = 0.f, S = 0.f, T = 0.f;
        #pragma unroll
        for (int w = 0; w < 4; ++w) {
            I += s_red[w * 3 + 0];
            S += s_red[w * 3 + 1];
            T += s_red[w * 3 + 2];
        }
        partials[blockIdx.x * 3 + 0] = I;
        partials[blockIdx.x * 3 + 1] = S;
        partials[blockIdx.x * 3 + 2] = T;
    }
}

__global__ __launch_bounds__(512)
void loss_mean_kernel(const float* __restrict__ partials, float* __restrict__ out, int n)
{
    __shared__ float s_red[8];
    float v = 0.f;
    for (int i = threadIdx.x; i < n; i += 512) {
        float I = 0.f, S = 0.f, T = 0.f;
        #pragma unroll
        for (int s = 0; s < NSLICE; ++s) {
            const float* p = partials + (size_t)(i * NSLICE + s) * 3;
            I += p[0];
            S += p[1];
            T += p[2];
        }
        v += 1.f - 2.f * I / (S + T + EPSV);
    }
    #pragma unroll
    for (int off = 32; off > 0; off >>= 1) v += __shfl_down(v, off, 64);
    const int wid = threadIdx.x >> 6;
    if ((threadIdx.x & 63) == 0) s_red[wid] = v;
    __syncthreads();
    if (threadIdx.x == 0) {
        float s = 0.f;
        #pragma unroll
        for (int w = 0; w < 8; ++w) s += s_red[w];
        out[0] = s / (float)n;
    }
}

extern "C" void kernel_launch(void* const* d_in, const int* in_sizes, int n_in,
                              void* d_out, int out_size, void* d_ws, size_t ws_size,
                              hipStream_t stream)
{
    const float* mask_feats = (const float*)d_in[0];
    const float* params     = (const float*)d_in[1];
    const float* locs       = (const float*)d_in[2];
    const float* gt         = (const float*)d_in[3];
    const int*   im_inds    = (const int*)d_in[4];
    const int*   fpn_levels = (const int*)d_in[5];
    // d_in[6] = mask_feat_stride (always 8 for this problem)

    const int n = in_sizes[4];          // 500 instances

    // d_ws layout: [0, n*NPIX) logits ; then partials (n*4*3 floats)
    float* logits   = (float*)d_ws;
    float* partials = logits + (size_t)n * NPIX;

    mask_logits<<<n * NSLICE, 256, 0, stream>>>(mask_feats, params, locs,
                                                im_inds, fpn_levels, logits);
    dice_reduce<<<n * NSLICE, 256, 0, stream>>>(logits, gt, partials);
    loss_mean_kernel<<<1, 512, 0, stream>>>(partials, (float*)d_out, n);
}

// Round 8
// 181.625 us; speedup vs baseline: 1.1772x; 1.1772x over previous
//
#include <hip/hip_runtime.h>
#include <hip/hip_bf16.h>
#include <math.h>

// Problem constants (fixed by setup_inputs)
#define CIN      8
#define H_IN     100
#define W_IN     136
#define NPIX     (H_IN * W_IN)       // 13600
#define OH       (2 * H_IN)          // 200
#define OW       (2 * W_IN)          // 272
#define ONPIX    (OH * OW)           // 54400
#define NPARAMS  169
#define EPSV     1e-5f
#define NSLICE   4                   // row-slices per instance
#define KG4      34                  // 136/4 col-groups of 4 src px
#define KGROUPS  34                  // 272/8 output col-groups
#define TASKS_B  (25 * KGROUPS)      // 850 phase-B tasks per slice

// param layout: w0[8][10] @0, w1[8][8] @80, w2[8] @144, b0 @152, b1 @160, b2 @168

__device__ __forceinline__ float sigmoidf_fast(float x) {
    float e = __expf(-x);
    return __builtin_amdgcn_rcpf(1.f + e);
}

// Session resource law: >85 VGPR -> 2 waves/SIMD (20% occ); <=64 -> 4 (45%).
// R2: capping fat code (needs 112) at 64 -> 1.8 GB spill. R4: capping scalar-
// load code at 85 -> compiler collapsed to 28 and serialized. This version is
// RESTRUCTURED to need only ~75 regs (two 4-channel load batches instead of 8
// in flight), so the (256,3) cap of 85 is naturally met -> 3 waves/SIMD.
__global__ __launch_bounds__(256, 3)
void mask_head_fused(const float* __restrict__ mask_feats,   // [N,8,100,136]
                     const float* __restrict__ params,       // [n,169]
                     const float* __restrict__ locs,         // [n,2]
                     const float* __restrict__ gt,           // [n,1,200,272]
                     const int*   __restrict__ im_inds,      // [n]
                     const int*   __restrict__ fpn_levels,   // [n]
                     float*       __restrict__ partials)     // [n*4][3]
{
    const int inst  = blockIdx.x >> 2;
    const int slice = blockIdx.x & 3;
    const int tid   = threadIdx.x;

    // src rows for this slice: max(25*slice-1,0) .. 25*slice+24
    const int r_start = (slice == 0) ? 0 : 25 * slice - 1;
    const int nrows   = (slice == 0) ? 25 : 26;
    const int ntask   = nrows * KG4;               // <= 884

    __shared__ float s_logit[26 * W_IN];           // 14144 B
    __shared__ float s_red[12];

    // Block-uniform weight pointer -> scalar K$ loads, zero VALU/LDS cost.
    const float* __restrict__ wp = params + (size_t)inst * NPARAMS;

    const int   im  = im_inds[inst];
    const int   lvl = fpn_levels[inst];
    const float inv_soi = exp2f(-(float)(3 + lvl));  // SOI = 8*2^lvl, exact
    const float lx = locs[inst * 2 + 0];
    const float ly = locs[inst * 2 + 1];
    const float dx8 = 8.f * inv_soi;

    const float* feat = mask_feats + (size_t)im * (CIN * NPIX);
    const int goff = r_start * W_IN;   // global pixel offset of local row 0

    // ---------------- Phase A: logits -> LDS ----------------
    // Task = 4 consecutive px in one row. Channel loads in TWO batches of 4
    // float4s: batch-2 flies while batch-1 feeds FMAs (intra-task pipeline,
    // peak ~74 live VGPRs).
    #pragma unroll 1
    for (int it = 0; it < 4; ++it) {
        const int t = it * 256 + tid;
        const bool valid = t < ntask;
        const int tc = valid ? t : ntask - 1;
        const int r  = tc / KG4;                   // local row
        const int k  = tc - r * KG4;               // col-group
        const int lpx = r * W_IN + 4 * k;
        const float* fb = feat + (goff + lpx);

        // batch 1: channels 0-3 (16 regs in flight)
        const float4 f0 = *(const float4*)(fb);
        const float4 f1 = *(const float4*)(fb + NPIX);
        const float4 f2 = *(const float4*)(fb + 2 * NPIX);
        const float4 f3 = *(const float4*)(fb + 3 * NPIX);

        // accumulator init from rel-coords while batch 1 is in flight
        float in0[4];
        in0[0] = (lx - (float)(32 * k + 4)) * inv_soi;
        in0[1] = in0[0] - dx8;
        in0[2] = in0[1] - dx8;
        in0[3] = in0[2] - dx8;
        const float in1 = (ly - (float)((r_start + r) * 8 + 4)) * inv_soi;

        float a[8][4];
        #pragma unroll
        for (int o = 0; o < 8; ++o) {
            const float base = fmaf(wp[o * 10 + 1], in1, wp[152 + o]);
            const float w0 = wp[o * 10];
            #pragma unroll
            for (int j = 0; j < 4; ++j)
                a[o][j] = fmaf(w0, in0[j], base);
        }

        // batch 2: channels 4-7 issued before batch 1 is consumed
        const float4 f4 = *(const float4*)(fb + 4 * NPIX);
        const float4 f5 = *(const float4*)(fb + 5 * NPIX);
        const float4 f6 = *(const float4*)(fb + 6 * NPIX);
        const float4 f7 = *(const float4*)(fb + 7 * NPIX);

        // consume: channel-major so each float4 dies after its 32 FMAs
#define CHFMA(FC, C)                                                    \
        {                                                               \
            _Pragma("unroll")                                           \
            for (int o = 0; o < 8; ++o) {                               \
                const float w = wp[o * 10 + 2 + (C)];                   \
                a[o][0] = fmaf(w, FC.x, a[o][0]);                       \
                a[o][1] = fmaf(w, FC.y, a[o][1]);                       \
                a[o][2] = fmaf(w, FC.z, a[o][2]);                       \
                a[o][3] = fmaf(w, FC.w, a[o][3]);                       \
            }                                                           \
        }
        CHFMA(f0, 0) CHFMA(f1, 1) CHFMA(f2, 2) CHFMA(f3, 3)
        CHFMA(f4, 4) CHFMA(f5, 5) CHFMA(f6, 6) CHFMA(f7, 7)
#undef CHFMA

        #pragma unroll
        for (int o = 0; o < 8; ++o)
            #pragma unroll
            for (int j = 0; j < 4; ++j)
                a[o][j] = fmaxf(a[o][j], 0.f);

        // layer 1: 8 -> 8 (relu folded into layer-2 consumption)
        float h[8][4];
        #pragma unroll
        for (int o = 0; o < 8; ++o) {
            const float b = wp[160 + o];
            #pragma unroll
            for (int j = 0; j < 4; ++j) h[o][j] = b;
        }
        #pragma unroll
        for (int i = 0; i < 8; ++i) {
            #pragma unroll
            for (int o = 0; o < 8; ++o) {
                const float w = wp[80 + o * 8 + i];
                #pragma unroll
                for (int j = 0; j < 4; ++j)
                    h[o][j] = fmaf(w, a[i][j], h[o][j]);
            }
        }

        // layer 2: 8 -> 1
        const float b2 = wp[168];
        float o4[4] = {b2, b2, b2, b2};
        #pragma unroll
        for (int i = 0; i < 8; ++i) {
            const float w = wp[144 + i];
            #pragma unroll
            for (int j = 0; j < 4; ++j)
                o4[j] = fmaf(w, fmaxf(h[i][j], 0.f), o4[j]);
        }

        if (valid) {
            float4 ov = {o4[0], o4[1], o4[2], o4[3]};
            *(float4*)(s_logit + lpx) = ov;   // 16B-aligned
        }
    }

    __syncthreads();

    // ---------------- Phase B: structured x2 upsample + sigmoid + dice ----------
    // Output row 2p   = avg(src row p-1, src row p)   (p=0: src row 0)
    // Output row 2p+1 = src row p
    // Output cols: o[2j]=avg of adjacent src cols, o[2j+1]=src col (left edge clamp)
    float inter = 0.f, ssum = 0.f, tsum = 0.f;
    const float* gtp = gt + (size_t)inst * ONPIX;
    const int pair_base = 25 * slice;

    #pragma unroll 1
    for (int base = 0; base < TASKS_B; base += 256) {
        const int task = base + tid;
        if (task < TASKS_B) {
            const int pl = task / KGROUPS;
            const int k  = task - pl * KGROUPS;
            const int pg = pair_base + pl;
            const int er = pg - r_start;                       // exact src row (local)
            const int pr = (pg > 0 ? pg - 1 : 0) - r_start;    // prev src row (local)
            const float* E = s_logit + er * W_IN;
            const float* P = s_logit + pr * W_IN;
            const int c0  = 4 * k;
            const int cm1 = (k > 0) ? c0 - 1 : 0;

            // issue all loads upfront
            const float* g0 = gtp + (size_t)(2 * pg) * OW + 8 * k;
            const float4 ga = *(const float4*)(g0);            // avg row, cols 0-3
            const float4 gb = *(const float4*)(g0 + 4);        // avg row, cols 4-7
            const float4 gc = *(const float4*)(g0 + OW);       // exact row, cols 0-3
            const float4 gd = *(const float4*)(g0 + OW + 4);   // exact row, cols 4-7
            const float4 e4 = *(const float4*)(E + c0);
            const float  em = E[cm1];
            const float4 p4 = *(const float4*)(P + c0);
            const float  pm = P[cm1];

            const float ecur[4] = {e4.x, e4.y, e4.z, e4.w};
            const float pcur[4] = {p4.x, p4.y, p4.z, p4.w};
            const float gav[8] = {ga.x, ga.y, ga.z, ga.w, gb.x, gb.y, gb.z, gb.w};
            const float gex[8] = {gc.x, gc.y, gc.z, gc.w, gd.x, gd.y, gd.z, gd.w};

            float Se_prev = em;
            float Sa_prev = 0.5f * (em + pm);
            #pragma unroll
            for (int j = 0; j < 4; ++j) {
                const float Se = ecur[j];
                const float Sa = 0.5f * (ecur[j] + pcur[j]);
                {
                    float s = sigmoidf_fast(0.5f * (Sa_prev + Sa));
                    float t2 = gav[2 * j];
                    inter = fmaf(s, t2, inter); ssum = fmaf(s, s, ssum); tsum = fmaf(t2, t2, tsum);
                    s = sigmoidf_fast(Sa);
                    t2 = gav[2 * j + 1];
                    inter = fmaf(s, t2, inter); ssum = fmaf(s, s, ssum); tsum = fmaf(t2, t2, tsum);
                }
                {
                    float s = sigmoidf_fast(0.5f * (Se_prev + Se));
                    float t2 = gex[2 * j];
                    inter = fmaf(s, t2, inter); ssum = fmaf(s, s, ssum); tsum = fmaf(t2, t2, tsum);
                    s = sigmoidf_fast(Se);
                    t2 = gex[2 * j + 1];
                    inter = fmaf(s, t2, inter); ssum = fmaf(s, s, ssum); tsum = fmaf(t2, t2, tsum);
                }
                Se_prev = Se;
                Sa_prev = Sa;
            }
        }
    }

    // block reduction (4 waves of 64)
    #pragma unroll
    for (int off = 32; off > 0; off >>= 1) {
        inter += __shfl_down(inter, off, 64);
        ssum  += __shfl_down(ssum,  off, 64);
        tsum  += __shfl_down(tsum,  off, 64);
    }
    const int wid = tid >> 6;
    if ((tid & 63) == 0) {
        s_red[wid * 3 + 0] = inter;
        s_red[wid * 3 + 1] = ssum;
        s_red[wid * 3 + 2] = tsum;
    }
    __syncthreads();
    if (tid == 0) {
        float I = 0.f, S = 0.f, T = 0.f;
        #pragma unroll
        for (int w = 0; w < 4; ++w) {
            I += s_red[w * 3 + 0];
            S += s_red[w * 3 + 1];
            T += s_red[w * 3 + 2];
        }
        partials[blockIdx.x * 3 + 0] = I;
        partials[blockIdx.x * 3 + 1] = S;
        partials[blockIdx.x * 3 + 2] = T;
    }
}

__global__ __launch_bounds__(512)
void loss_mean_kernel(const float* __restrict__ partials, float* __restrict__ out, int n)
{
    __shared__ float s_red[8];
    float v = 0.f;
    for (int i = threadIdx.x; i < n; i += 512) {
        float I = 0.f, S = 0.f, T = 0.f;
        #pragma unroll
        for (int s = 0; s < NSLICE; ++s) {
            const float* p = partials + (size_t)(i * NSLICE + s) * 3;
            I += p[0];
            S += p[1];
            T += p[2];
        }
        v += 1.f - 2.f * I / (S + T + EPSV);
    }
    #pragma unroll
    for (int off = 32; off > 0; off >>= 1) v += __shfl_down(v, off, 64);
    const int wid = threadIdx.x >> 6;
    if ((threadIdx.x & 63) == 0) s_red[wid] = v;
    __syncthreads();
    if (threadIdx.x == 0) {
        float s = 0.f;
        #pragma unroll
        for (int w = 0; w < 8; ++w) s += s_red[w];
        out[0] = s / (float)n;
    }
}

extern "C" void kernel_launch(void* const* d_in, const int* in_sizes, int n_in,
                              void* d_out, int out_size, void* d_ws, size_t ws_size,
                              hipStream_t stream)
{
    const float* mask_feats = (const float*)d_in[0];
    const float* params     = (const float*)d_in[1];
    const float* locs       = (const float*)d_in[2];
    const float* gt         = (const float*)d_in[3];
    const int*   im_inds    = (const int*)d_in[4];
    const int*   fpn_levels = (const int*)d_in[5];
    // d_in[6] = mask_feat_stride (always 8 for this problem)

    const int n = in_sizes[4];          // 500 instances
    float* partials = (float*)d_ws;     // n*NSLICE*3 floats

    mask_head_fused<<<n * NSLICE, 256, 0, stream>>>(mask_feats, params, locs, gt,
                                                    im_inds, fpn_levels, partials);
    loss_mean_kernel<<<1, 512, 0, stream>>>(partials, (float*)d_out, n);
}

// Round 9
// 181.536 us; speedup vs baseline: 1.1778x; 1.0005x over previous
//
#include <hip/hip_runtime.h>
#include <hip/hip_bf16.h>
#include <math.h>

// Problem constants (fixed by setup_inputs)
#define CIN      8
#define H_IN     100
#define W_IN     136
#define NPIX     (H_IN * W_IN)       // 13600
#define OH       (2 * H_IN)          // 200
#define OW       (2 * W_IN)          // 272
#define ONPIX    (OH * OW)           // 54400
#define NPARAMS  169
#define EPSV     1e-5f
#define NSLICE   4                   // row-slices per instance
#define KG4      34                  // 136/4 col-groups of 4 src px
#define KGROUPS  34                  // 272/8 output col-groups
#define TASKS_B  (25 * KGROUPS)      // 850 phase-B tasks per slice

// param layout: w0[8][10] @0, w1[8][8] @80, w2[8] @144, b0 @152, b1 @160, b2 @168

__device__ __forceinline__ float sigmoidf_fast(float x) {
    float e = __expf(-x);
    return __builtin_amdgcn_rcpf(1.f + e);
}

// Occupancy law (session-calibrated): waves/SIMD ~= 256/VGPR.
// Caps: (256,2)=128, (256,3)=85, (256,4)=64. R2: squeezing 112-natural code
// to 64 -> catastrophic spill. This version is restructured to need ~58
// naturally (no h[8][4]; per-px MLP with fused layers 1+2), so (256,4) is a
// legitimate 4-waves/SIMD fit, not a forced squeeze.
__global__ __launch_bounds__(256, 4)
void mask_head_fused(const float* __restrict__ mask_feats,   // [N,8,100,136]
                     const float* __restrict__ params,       // [n,169]
                     const float* __restrict__ locs,         // [n,2]
                     const float* __restrict__ gt,           // [n,1,200,272]
                     const int*   __restrict__ im_inds,      // [n]
                     const int*   __restrict__ fpn_levels,   // [n]
                     float*       __restrict__ partials)     // [n*4][3]
{
    const int inst  = blockIdx.x >> 2;
    const int slice = blockIdx.x & 3;
    const int tid   = threadIdx.x;

    // src rows for this slice: max(25*slice-1,0) .. 25*slice+24
    const int r_start = (slice == 0) ? 0 : 25 * slice - 1;
    const int nrows   = (slice == 0) ? 25 : 26;
    const int ntask   = nrows * KG4;               // <= 884

    __shared__ float s_logit[26 * W_IN];           // 14144 B
    __shared__ float s_red[12];

    // Block-uniform weight pointer -> scalar K$ loads, zero VALU/LDS cost.
    const float* __restrict__ wp = params + (size_t)inst * NPARAMS;

    const int   im  = im_inds[inst];
    const int   lvl = fpn_levels[inst];
    const float inv_soi = exp2f(-(float)(3 + lvl));  // SOI = 8*2^lvl, exact
    const float lx = locs[inst * 2 + 0];
    const float ly = locs[inst * 2 + 1];
    const float dx8 = 8.f * inv_soi;

    const float* feat = mask_feats + (size_t)im * (CIN * NPIX);
    const int goff = r_start * W_IN;   // global pixel offset of local row 0

    // ---------------- Phase A: logits -> LDS ----------------
    // Task = 4 consecutive px in one row. All 8 channel float4s issued upfront
    // (32 dedicated regs — cannot be load-serialized), then the 4 px are
    // processed SERIALLY, each with only aj[8] live. Layers 1+2 fused per
    // output channel (no h[8][4] array). Peak ~58 VGPR.
    #pragma unroll 1
    for (int it = 0; it < 4; ++it) {
        const int t = it * 256 + tid;
        const bool valid = t < ntask;
        const int tc = valid ? t : ntask - 1;
        const int r  = tc / KG4;                   // local row
        const int k  = tc - r * KG4;               // col-group
        const int lpx = r * W_IN + 4 * k;
        const float* fb = feat + (goff + lpx);

        // all 8 channel loads in flight together
        float4 f[8];
        #pragma unroll
        for (int c = 0; c < CIN; ++c)
            f[c] = *(const float4*)(fb + c * NPIX);

        float in0[4];
        in0[0] = (lx - (float)(32 * k + 4)) * inv_soi;
        in0[1] = in0[0] - dx8;
        in0[2] = in0[1] - dx8;
        in0[3] = in0[2] - dx8;
        const float in1 = (ly - (float)((r_start + r) * 8 + 4)) * inv_soi;

        float o4[4];

#define DO_PX(J, COMP)                                                        \
        {                                                                     \
            float aj[8];                                                      \
            _Pragma("unroll")                                                 \
            for (int o = 0; o < 8; ++o)                                       \
                aj[o] = fmaf(wp[o * 10], in0[J],                              \
                             fmaf(wp[o * 10 + 1], in1, wp[152 + o]));         \
            _Pragma("unroll")                                                 \
            for (int c = 0; c < 8; ++c) {                                     \
                _Pragma("unroll")                                             \
                for (int o = 0; o < 8; ++o)                                   \
                    aj[o] = fmaf(wp[o * 10 + 2 + c], f[c].COMP, aj[o]);       \
            }                                                                 \
            _Pragma("unroll")                                                 \
            for (int o = 0; o < 8; ++o)                                       \
                aj[o] = fmaxf(aj[o], 0.f);                                    \
            float acc = wp[168];                                              \
            _Pragma("unroll")                                                 \
            for (int o = 0; o < 8; ++o) {                                     \
                float tt = wp[160 + o];                                       \
                _Pragma("unroll")                                             \
                for (int i = 0; i < 8; ++i)                                   \
                    tt = fmaf(wp[80 + o * 8 + i], aj[i], tt);                 \
                acc = fmaf(wp[144 + o], fmaxf(tt, 0.f), acc);                 \
            }                                                                 \
            o4[J] = acc;                                                      \
        }

        DO_PX(0, x)
        DO_PX(1, y)
        DO_PX(2, z)
        DO_PX(3, w)
#undef DO_PX

        if (valid) {
            float4 ov = {o4[0], o4[1], o4[2], o4[3]};
            *(float4*)(s_logit + lpx) = ov;   // 16B-aligned
        }
    }

    __syncthreads();

    // ---------------- Phase B: structured x2 upsample + sigmoid + dice ----------
    // Output row 2p   = avg(src row p-1, src row p)   (p=0: src row 0)
    // Output row 2p+1 = src row p
    // Output cols: o[2j]=avg of adjacent src cols, o[2j+1]=src col (left edge clamp)
    float inter = 0.f, ssum = 0.f, tsum = 0.f;
    const float* gtp = gt + (size_t)inst * ONPIX;
    const int pair_base = 25 * slice;

    #pragma unroll 1
    for (int base = 0; base < TASKS_B; base += 256) {
        const int task = base + tid;
        if (task < TASKS_B) {
            const int pl = task / KGROUPS;
            const int k  = task - pl * KGROUPS;
            const int pg = pair_base + pl;
            const int er = pg - r_start;                       // exact src row (local)
            const int pr = (pg > 0 ? pg - 1 : 0) - r_start;    // prev src row (local)
            const float* E = s_logit + er * W_IN;
            const float* P = s_logit + pr * W_IN;
            const int c0  = 4 * k;
            const int cm1 = (k > 0) ? c0 - 1 : 0;

            // issue all loads upfront
            const float* g0 = gtp + (size_t)(2 * pg) * OW + 8 * k;
            const float4 ga = *(const float4*)(g0);            // avg row, cols 0-3
            const float4 gb = *(const float4*)(g0 + 4);        // avg row, cols 4-7
            const float4 gc = *(const float4*)(g0 + OW);       // exact row, cols 0-3
            const float4 gd = *(const float4*)(g0 + OW + 4);   // exact row, cols 4-7
            const float4 e4 = *(const float4*)(E + c0);
            const float  em = E[cm1];
            const float4 p4 = *(const float4*)(P + c0);
            const float  pm = P[cm1];

            const float ecur[4] = {e4.x, e4.y, e4.z, e4.w};
            const float pcur[4] = {p4.x, p4.y, p4.z, p4.w};
            const float gav[8] = {ga.x, ga.y, ga.z, ga.w, gb.x, gb.y, gb.z, gb.w};
            const float gex[8] = {gc.x, gc.y, gc.z, gc.w, gd.x, gd.y, gd.z, gd.w};

            float Se_prev = em;
            float Sa_prev = 0.5f * (em + pm);
            #pragma unroll
            for (int j = 0; j < 4; ++j) {
                const float Se = ecur[j];
                const float Sa = 0.5f * (ecur[j] + pcur[j]);
                {
                    float s = sigmoidf_fast(0.5f * (Sa_prev + Sa));
                    float t2 = gav[2 * j];
                    inter = fmaf(s, t2, inter); ssum = fmaf(s, s, ssum); tsum = fmaf(t2, t2, tsum);
                    s = sigmoidf_fast(Sa);
                    t2 = gav[2 * j + 1];
                    inter = fmaf(s, t2, inter); ssum = fmaf(s, s, ssum); tsum = fmaf(t2, t2, tsum);
                }
                {
                    float s = sigmoidf_fast(0.5f * (Se_prev + Se));
                    float t2 = gex[2 * j];
                    inter = fmaf(s, t2, inter); ssum = fmaf(s, s, ssum); tsum = fmaf(t2, t2, tsum);
                    s = sigmoidf_fast(Se);
                    t2 = gex[2 * j + 1];
                    inter = fmaf(s, t2, inter); ssum = fmaf(s, s, ssum); tsum = fmaf(t2, t2, tsum);
                }
                Se_prev = Se;
                Sa_prev = Sa;
            }
        }
    }

    // block reduction (4 waves of 64)
    #pragma unroll
    for (int off = 32; off > 0; off >>= 1) {
        inter += __shfl_down(inter, off, 64);
        ssum  += __shfl_down(ssum,  off, 64);
        tsum  += __shfl_down(tsum,  off, 64);
    }
    const int wid = tid >> 6;
    if ((tid & 63) == 0) {
        s_red[wid * 3 + 0] = inter;
        s_red[wid * 3 + 1] = ssum;
        s_red[wid * 3 + 2] = tsum;
    }
    __syncthreads();
    if (tid == 0) {
        float I = 0.f, S = 0.f, T = 0.f;
        #pragma unroll
        for (int w = 0; w < 4; ++w) {
            I += s_red[w * 3 + 0];
            S += s_red[w * 3 + 1];
            T += s_red[w * 3 + 2];
        }
        partials[blockIdx.x * 3 + 0] = I;
        partials[blockIdx.x * 3 + 1] = S;
        partials[blockIdx.x * 3 + 2] = T;
    }
}

__global__ __launch_bounds__(512)
void loss_mean_kernel(const float* __restrict__ partials, float* __restrict__ out, int n)
{
    __shared__ float s_red[8];
    float v = 0.f;
    for (int i = threadIdx.x; i < n; i += 512) {
        float I = 0.f, S = 0.f, T = 0.f;
        #pragma unroll
        for (int s = 0; s < NSLICE; ++s) {
            const float* p = partials + (size_t)(i * NSLICE + s) * 3;
            I += p[0];
            S += p[1];
            T += p[2];
        }
        v += 1.f - 2.f * I / (S + T + EPSV);
    }
    #pragma unroll
    for (int off = 32; off > 0; off >>= 1) v += __shfl_down(v, off, 64);
    const int wid = threadIdx.x >> 6;
    if ((threadIdx.x & 63) == 0) s_red[wid] = v;
    __syncthreads();
    if (threadIdx.x == 0) {
        float s = 0.f;
        #pragma unroll
        for (int w = 0; w < 8; ++w) s += s_red[w];
        out[0] = s / (float)n;
    }
}

extern "C" void kernel_launch(void* const* d_in, const int* in_sizes, int n_in,
                              void* d_out, int out_size, void* d_ws, size_t ws_size,
                              hipStream_t stream)
{
    const float* mask_feats = (const float*)d_in[0];
    const float* params     = (const float*)d_in[1];
    const float* locs       = (const float*)d_in[2];
    const float* gt         = (const float*)d_in[3];
    const int*   im_inds    = (const int*)d_in[4];
    const int*   fpn_levels = (const int*)d_in[5];
    // d_in[6] = mask_feat_stride (always 8 for this problem)

    const int n = in_sizes[4];          // 500 instances
    float* partials = (float*)d_ws;     // n*NSLICE*3 floats

    mask_head_fused<<<n * NSLICE, 256, 0, stream>>>(mask_feats, params, locs, gt,
                                                    im_inds, fpn_levels, partials);
    loss_mean_kernel<<<1, 512, 0, stream>>>(partials, (float*)d_out, n);
}